// Round 1
// baseline (179.634 us; speedup 1.0000x reference)
//
#include <hip/hip_runtime.h>
#include <math.h>

// QuanvolutionHybridGraphQL:
//   q   = cos(2x2 patches of 28x28 img)            -> (B,196,4)
//   qn  = q / (||q||_2 + 1e-12)
//   fid = (qn . qn^T)^2                             -> (B,196,196)
//   adj = fid>=0.8 ? 1 : fid>=0.5 ? 0.5 : 0 ; diag=0
//   logits = (mean_n q @ W1 + b1) @ W2 + b2         -> (B,10)
// Output = concat(logits flat, adj flat).
// adj is 629 MB fp32 -> kernel is HBM-write bound (~100us floor).

#define NP   196
#define NPIX 784
#define BLK  256

__global__ __launch_bounds__(BLK) void quanv_kernel(
    const float* __restrict__ x,
    const float* __restrict__ W1, const float* __restrict__ b1,
    const float* __restrict__ W2, const float* __restrict__ b2,
    float* __restrict__ logits, float* __restrict__ adj)
{
    __shared__ float q4[NP][4];     // q, patch-major (for pooled reduction)
    __shared__ float qnT[4][NP];    // qn, dim-major (conflict-free m-reads)
    __shared__ float pooled[4];

    const int b   = blockIdx.x;
    const int tid = threadIdx.x;
    const float* img = x + (size_t)b * NPIX;

    // 1) coalesced pixel load -> cos -> q in LDS
    for (int p = tid; p < NPIX; p += BLK) {
        int r = p / 28;
        int c = p - r * 28;
        int n  = (r >> 1) * 14 + (c >> 1);       // patch index
        int dd = ((r & 1) << 1) | (c & 1);       // element within patch
        q4[n][dd] = cosf(img[p]);
    }
    __syncthreads();

    // 2) per-patch L2-normalize into transposed layout
    if (tid < NP) {
        float a0 = q4[tid][0], a1 = q4[tid][1], a2 = q4[tid][2], a3 = q4[tid][3];
        float nrm = sqrtf(a0*a0 + a1*a1 + a2*a2 + a3*a3);
        float inv = 1.0f / (nrm + 1e-12f);
        qnT[0][tid] = a0 * inv;
        qnT[1][tid] = a1 * inv;
        qnT[2][tid] = a2 * inv;
        qnT[3][tid] = a3 * inv;
    }

    // 3) pooled = mean_n q  (wave 0 only: partial sums + shuffle reduce)
    if (tid < 64) {
        float s0 = 0.f, s1 = 0.f, s2 = 0.f, s3 = 0.f;
        for (int n = tid; n < NP; n += 64) {
            s0 += q4[n][0]; s1 += q4[n][1]; s2 += q4[n][2]; s3 += q4[n][3];
        }
        #pragma unroll
        for (int off = 32; off >= 1; off >>= 1) {
            s0 += __shfl_down(s0, off);
            s1 += __shfl_down(s1, off);
            s2 += __shfl_down(s2, off);
            s3 += __shfl_down(s3, off);
        }
        if (tid == 0) {
            pooled[0] = s0 * (1.0f / NP);
            pooled[1] = s1 * (1.0f / NP);
            pooled[2] = s2 * (1.0f / NP);
            pooled[3] = s3 * (1.0f / NP);
        }
    }
    __syncthreads();

    // 4) tiny MLP: logits = (pooled @ W1 + b1) @ W2 + b2
    if (tid < 10) {
        float p0 = pooled[0], p1 = pooled[1], p2 = pooled[2], p3 = pooled[3];
        float acc = b2[tid];
        #pragma unroll
        for (int k = 0; k < 32; ++k) {
            float h = b1[k] + p0 * W1[0*32 + k] + p1 * W1[1*32 + k]
                            + p2 * W1[2*32 + k] + p3 * W1[3*32 + k];
            acc += h * W2[k*10 + tid];
        }
        logits[(size_t)b * 10 + tid] = acc;
    }

    // 5) adj: flat grid-stride over 196*196, coalesced scalar stores
    float* out = adj + (size_t)b * (NP * NP);
    for (int e = tid; e < NP * NP; e += BLK) {
        int n = e / NP;              // compiler magic-div
        int m = e - n * NP;
        float dot = qnT[0][n] * qnT[0][m]
                  + qnT[1][n] * qnT[1][m]
                  + qnT[2][n] * qnT[2][m]
                  + qnT[3][n] * qnT[3][m];
        float fid = dot * dot;
        float val = (fid >= 0.8f) ? 1.0f : ((fid >= 0.5f) ? 0.5f : 0.0f);
        out[e] = (n == m) ? 0.0f : val;
    }
}

extern "C" void kernel_launch(void* const* d_in, const int* in_sizes, int n_in,
                              void* d_out, int out_size, void* d_ws, size_t ws_size,
                              hipStream_t stream) {
    const float* x  = (const float*)d_in[0];
    const float* W1 = (const float*)d_in[1];
    const float* b1 = (const float*)d_in[2];
    const float* W2 = (const float*)d_in[3];
    const float* b2 = (const float*)d_in[4];

    const int B = in_sizes[0] / NPIX;          // 4096
    float* logits = (float*)d_out;             // B*10
    float* adj    = logits + (size_t)B * 10;   // B*196*196

    quanv_kernel<<<B, BLK, 0, stream>>>(x, W1, b1, W2, b2, logits, adj);
}

// Round 3
// 140.144 us; speedup vs baseline: 1.2818x; 1.2818x over previous
//
#include <hip/hip_runtime.h>
#include <math.h>

// QuanvolutionHybridGraphQL:
//   q   = cos(2x2 patches of 28x28 img)            -> (B,196,4)
//   qn  = q / (||q||_2 + 1e-12)
//   fid = (qn . qn^T)^2                             -> (B,196,196)
//   adj = fid>=0.8 ? 1 : fid>=0.5 ? 0.5 : 0 ; diag=0
//   logits = (mean_n q @ W1 + b1) @ W2 + b2         -> (B,10)
// Output = concat(logits flat, adj flat).
// adj is 629 MB fp32 -> HBM-write bound. Fill kernel calibrates ceiling
// at ~6.6 TB/s -> ~97us floor. R1: scalar stores -> 179us (55% of BW).
// R2/R3: float4 nontemporal stores (196 = 49*4 -> rows float4-aligned);
// use clang ext_vector_type since __builtin_nontemporal_store rejects
// HIP_vector_type.

#define NP   196
#define NPIX 784
#define BLK  256
#define NV   (NP * NP / 4)   // 9604 float4 per image
#define VPR  (NP / 4)        // 49 float4 per row

typedef float f32x4 __attribute__((ext_vector_type(4)));

__global__ __launch_bounds__(BLK) void quanv_kernel(
    const float* __restrict__ x,
    const float* __restrict__ W1, const float* __restrict__ b1,
    const float* __restrict__ W2, const float* __restrict__ b2,
    float* __restrict__ logits, float* __restrict__ adj)
{
    __shared__ float q4[NP][4];                    // q, patch-major (pooled)
    __shared__ __align__(16) float qnT[4][NP];     // qn, dim-major
    __shared__ float pooled[4];

    const int b   = blockIdx.x;
    const int tid = threadIdx.x;
    const float* img = x + (size_t)b * NPIX;

    // 1) coalesced pixel load -> cos -> q in LDS
    for (int p = tid; p < NPIX; p += BLK) {
        int r = p / 28;
        int c = p - r * 28;
        int n  = (r >> 1) * 14 + (c >> 1);       // patch index
        int dd = ((r & 1) << 1) | (c & 1);       // element within patch
        q4[n][dd] = cosf(img[p]);
    }
    __syncthreads();

    // 2) per-patch L2-normalize into transposed (dim-major) layout
    if (tid < NP) {
        float a0 = q4[tid][0], a1 = q4[tid][1], a2 = q4[tid][2], a3 = q4[tid][3];
        float nrm = sqrtf(a0*a0 + a1*a1 + a2*a2 + a3*a3);
        float inv = 1.0f / (nrm + 1e-12f);
        qnT[0][tid] = a0 * inv;
        qnT[1][tid] = a1 * inv;
        qnT[2][tid] = a2 * inv;
        qnT[3][tid] = a3 * inv;
    }

    // 3) pooled = mean_n q  (wave 0: partial sums + shuffle reduce)
    if (tid < 64) {
        float s0 = 0.f, s1 = 0.f, s2 = 0.f, s3 = 0.f;
        for (int n = tid; n < NP; n += 64) {
            s0 += q4[n][0]; s1 += q4[n][1]; s2 += q4[n][2]; s3 += q4[n][3];
        }
        #pragma unroll
        for (int off = 32; off >= 1; off >>= 1) {
            s0 += __shfl_down(s0, off);
            s1 += __shfl_down(s1, off);
            s2 += __shfl_down(s2, off);
            s3 += __shfl_down(s3, off);
        }
        if (tid == 0) {
            pooled[0] = s0 * (1.0f / NP);
            pooled[1] = s1 * (1.0f / NP);
            pooled[2] = s2 * (1.0f / NP);
            pooled[3] = s3 * (1.0f / NP);
        }
    }
    __syncthreads();

    // 4) tiny MLP: logits = (pooled @ W1 + b1) @ W2 + b2
    if (tid < 10) {
        float p0 = pooled[0], p1 = pooled[1], p2 = pooled[2], p3 = pooled[3];
        float acc = b2[tid];
        #pragma unroll
        for (int k = 0; k < 32; ++k) {
            float h = b1[k] + p0 * W1[0*32 + k] + p1 * W1[1*32 + k]
                            + p2 * W1[2*32 + k] + p3 * W1[3*32 + k];
            acc += h * W2[k*10 + tid];
        }
        logits[(size_t)b * 10 + tid] = acc;
    }

    // 5) adj: float4-vectorized, nontemporal, coalesced stores.
    //    Row length 196 = 49*4 -> each float4 stays within one row n.
    f32x4* out4 = reinterpret_cast<f32x4*>(adj + (size_t)b * (NP * NP));
    for (int e4 = tid; e4 < NV; e4 += BLK) {
        int n  = e4 / VPR;                 // magic-div by 49
        int m0 = (e4 - n * VPR) * 4;

        float c0 = qnT[0][n], c1 = qnT[1][n], c2 = qnT[2][n], c3 = qnT[3][n];
        f32x4 v0 = *reinterpret_cast<const f32x4*>(&qnT[0][m0]);
        f32x4 v1 = *reinterpret_cast<const f32x4*>(&qnT[1][m0]);
        f32x4 v2 = *reinterpret_cast<const f32x4*>(&qnT[2][m0]);
        f32x4 v3 = *reinterpret_cast<const f32x4*>(&qnT[3][m0]);

        f32x4 d = c0*v0 + c1*v1 + c2*v2 + c3*v3;
        f32x4 f = d * d;

        f32x4 o;
        o.x = (f.x >= 0.8f) ? 1.0f : ((f.x >= 0.5f) ? 0.5f : 0.0f);
        o.y = (f.y >= 0.8f) ? 1.0f : ((f.y >= 0.5f) ? 0.5f : 0.0f);
        o.z = (f.z >= 0.8f) ? 1.0f : ((f.z >= 0.5f) ? 0.5f : 0.0f);
        o.w = (f.w >= 0.8f) ? 1.0f : ((f.w >= 0.5f) ? 0.5f : 0.0f);

        // zero the diagonal if it falls inside this float4
        if (n >= m0 && n < m0 + 4) {
            if      (n == m0)     o.x = 0.0f;
            else if (n == m0 + 1) o.y = 0.0f;
            else if (n == m0 + 2) o.z = 0.0f;
            else                  o.w = 0.0f;
        }
        __builtin_nontemporal_store(o, &out4[e4]);
    }
}

extern "C" void kernel_launch(void* const* d_in, const int* in_sizes, int n_in,
                              void* d_out, int out_size, void* d_ws, size_t ws_size,
                              hipStream_t stream) {
    const float* x  = (const float*)d_in[0];
    const float* W1 = (const float*)d_in[1];
    const float* b1 = (const float*)d_in[2];
    const float* W2 = (const float*)d_in[3];
    const float* b2 = (const float*)d_in[4];

    const int B = in_sizes[0] / NPIX;          // 4096
    float* logits = (float*)d_out;             // B*10
    float* adj    = logits + (size_t)B * 10;   // B*196*196

    quanv_kernel<<<B, BLK, 0, stream>>>(x, W1, b1, W2, b2, logits, adj);
}